// Round 1
// baseline (1180.373 us; speedup 1.0000x reference)
//
#include <hip/hip_runtime.h>
#include <cmath>

// Problem constants
#define BSZ   2048
#define TSTEP 64
#define HDIM  1024
#define RTOT  (BSZ * TSTEP)   // 131072 rows
#define MEMN  32

// ---------------------------------------------------------------------------
// Kernel 1: projection GEMM  (RTOT x HDIM) @ (HDIM x 97) -> G, Q, FK, FV
// Columns: 0..31 = query, 32..63 = fk, 64..95 = fv, 96 = gate (sigmoid applied)
// fp32 vector GEMM, 128x128 tile (cols padded with zeros), BK=32.
// ---------------------------------------------------------------------------
constexpr int BM = 128, BN = 128, BK = 32;

__global__ __launch_bounds__(256) void proj_kernel(
    const float* __restrict__ h,
    const float* __restrict__ Wg,  const float* __restrict__ bg,
    const float* __restrict__ Wq,  const float* __restrict__ bq,
    const float* __restrict__ Wfk, const float* __restrict__ bfk,
    const float* __restrict__ Wfv, const float* __restrict__ bfv,
    float* __restrict__ G, float* __restrict__ Qo,
    float* __restrict__ FKo, float* __restrict__ FVo)
{
    __shared__ __align__(16) float Xs[BK][BM + 4];  // transposed: Xs[k][m]
    __shared__ __align__(16) float Ws[BK][BN];      // transposed: Ws[k][n]

    const int tid  = threadIdx.x;
    const int tx   = tid & 15;    // 0..15 -> col groups
    const int ty   = tid >> 4;    // 0..15 -> row groups
    const int row0 = blockIdx.x * BM;

    float acc[8][8];
#pragma unroll
    for (int i = 0; i < 8; ++i)
#pragma unroll
        for (int j = 0; j < 8; ++j) acc[i][j] = 0.f;

    for (int k0 = 0; k0 < HDIM; k0 += BK) {
        // --- stage X tile: 128 rows x 32 k  (1024 float4 tasks, 4/thread) ---
#pragma unroll
        for (int it = 0; it < 4; ++it) {
            int task = tid + it * 256;
            int rr   = task >> 3;          // 0..127
            int kv   = (task & 7) << 2;    // 0,4,...,28
            const float4 xv = *reinterpret_cast<const float4*>(
                &h[(size_t)(row0 + rr) * HDIM + k0 + kv]);
            Xs[kv + 0][rr] = xv.x;
            Xs[kv + 1][rr] = xv.y;
            Xs[kv + 2][rr] = xv.z;
            Xs[kv + 3][rr] = xv.w;
        }
        // --- stage W tile: 128 n x 32 k (zero-pad n >= 97) ---
#pragma unroll
        for (int it = 0; it < 4; ++it) {
            int task = tid + it * 256;
            int nn   = task >> 3;
            int kv   = (task & 7) << 2;
            float4 wv = make_float4(0.f, 0.f, 0.f, 0.f);
            const float* src = nullptr;
            if (nn < 32)       src = Wq  + (size_t)nn * HDIM;
            else if (nn < 64)  src = Wfk + (size_t)(nn - 32) * HDIM;
            else if (nn < 96)  src = Wfv + (size_t)(nn - 64) * HDIM;
            else if (nn == 96) src = Wg;
            if (src) wv = *reinterpret_cast<const float4*>(&src[k0 + kv]);
            Ws[kv + 0][nn] = wv.x;
            Ws[kv + 1][nn] = wv.y;
            Ws[kv + 2][nn] = wv.z;
            Ws[kv + 3][nn] = wv.w;
        }
        __syncthreads();

#pragma unroll
        for (int k = 0; k < BK; ++k) {
            const float4 a0 = *reinterpret_cast<const float4*>(&Xs[k][ty * 4]);
            const float4 a1 = *reinterpret_cast<const float4*>(&Xs[k][64 + ty * 4]);
            const float4 b0 = *reinterpret_cast<const float4*>(&Ws[k][tx * 4]);
            const float4 b1 = *reinterpret_cast<const float4*>(&Ws[k][64 + tx * 4]);
            const float av[8] = {a0.x, a0.y, a0.z, a0.w, a1.x, a1.y, a1.z, a1.w};
            const float bv[8] = {b0.x, b0.y, b0.z, b0.w, b1.x, b1.y, b1.z, b1.w};
#pragma unroll
            for (int i = 0; i < 8; ++i)
#pragma unroll
                for (int j = 0; j < 8; ++j)
                    acc[i][j] = fmaf(av[i], bv[j], acc[i][j]);
        }
        __syncthreads();
    }

    // --- epilogue: scatter to G / Q / FK / FV with biases ---
#pragma unroll
    for (int i = 0; i < 8; ++i) {
        const int rl = (i < 4) ? (ty * 4 + i) : (64 + ty * 4 + (i - 4));
        const size_t r = (size_t)row0 + rl;
#pragma unroll
        for (int j = 0; j < 8; ++j) {
            const int c = (j < 4) ? (tx * 4 + j) : (64 + tx * 4 + (j - 4));
            const float v = acc[i][j];
            if (c < 32)        Qo [r * 32 + c]        = v + bq[c];
            else if (c < 64)   FKo[r * 32 + (c - 32)] = v + bfk[c - 32];
            else if (c < 96)   FVo[r * 32 + (c - 64)] = v + bfv[c - 64];
            else if (c == 96) {
                const float x = v + bg[0];
                G[r] = 1.f / (1.f + expf(-x));   // p_reuse
            }
        }
    }
}

// ---------------------------------------------------------------------------
// Kernel 2: recurrence. One 32-lane half-wave per batch element.
// Block = 128 threads = 4 batch elements. Grid = 2048/4 = 512.
// K,V in LDS (row padded to 33 -> conflict-free rows AND columns).
// Tf, mask live in registers (lane m owns slot m).
// ---------------------------------------------------------------------------
__global__ __launch_bounds__(128) void recur_kernel(
    const float* __restrict__ G,  const float* __restrict__ Qp,
    const float* __restrict__ FKp, const float* __restrict__ FVp,
    float* __restrict__ out)
{
    __shared__ float Ks[4][MEMN][33];
    __shared__ float Vs[4][MEMN][33];
    __shared__ float qs[4][MEMN];
    __shared__ float attn_s[4][MEMN];

    const int tid = threadIdx.x;
    const int el  = tid >> 5;          // 0..3 local batch element
    const int m   = tid & 31;          // slot index
    const size_t b = (size_t)blockIdx.x * 4 + el;

    // init state to zeros
#pragma unroll
    for (int k = 0; k < MEMN; ++k) { Ks[el][m][k] = 0.f; Vs[el][m][k] = 0.f; }
    float Tf  = 0.f;   // timer for slot m
    float msk = 0.f;   // mask for slot m
    __syncthreads();

    const float scale = 0.17677669529663687f;  // 1/sqrt(32)
    float* es_out = out;
    float* ps_out = out + (size_t)RTOT * 32;

    for (int t = 0; t < TSTEP; ++t) {
        const size_t r = b * TSTEP + t;
        const float q  = Qp [r * 32 + m];
        const float fk = FKp[r * 32 + m];
        const float fv = FVp[r * 32 + m];
        const float p  = G[r];             // p_reuse (sigmoid already applied)

        qs[el][m] = q;
        __syncthreads();   // staging visible + previous iter's K/V updates done

        // logits[m] = dot(K[m][:], q) * scale, masked
        float accv = 0.f;
#pragma unroll
        for (int k = 0; k < MEMN; ++k) accv = fmaf(Ks[el][m][k], qs[el][k], accv);
        const float lg = accv * scale + (1.f - msk) * (-1e9f);

        // softmax over 32 lanes (butterfly within half-wave)
        float mx = lg;
#pragma unroll
        for (int d = 16; d >= 1; d >>= 1) mx = fmaxf(mx, __shfl_xor(mx, d));
        const float pe = expf(lg - mx);
        float ssum = pe;
#pragma unroll
        for (int d = 16; d >= 1; d >>= 1) ssum += __shfl_xor(ssum, d);
        const float attn = pe / ssum;
        attn_s[el][m] = attn;

        // mask sum (for empty_row)
        float smk = msk;
#pragma unroll
        for (int d = 16; d >= 1; d >>= 1) smk += __shfl_xor(smk, d);

        // argmax(attn), first-index tie-break (matches jnp.argmax)
        float av = attn; int ai = m;
#pragma unroll
        for (int d = 16; d >= 1; d >>= 1) {
            const float ov = __shfl_xor(av, d);
            const int   oi = __shfl_xor(ai, d);
            if (ov > av || (ov == av && oi < ai)) { av = ov; ai = oi; }
        }
        // argmin(Tf + mask*0.001), first-index tie-break (matches jnp.argmin)
        float evv = Tf + msk * 0.001f; int ei = m;
#pragma unroll
        for (int d = 16; d >= 1; d >>= 1) {
            const float ov = __shfl_xor(evv, d);
            const int   oi = __shfl_xor(ei, d);
            if (ov < evv || (ov == evv && oi < ei)) { evv = ov; ei = oi; }
        }
        __syncthreads();   // attn_s visible

        // retrv[m] = sum_k attn[k] * V[k][m]   (column read, conflict-free)
        float rv = 0.f;
#pragma unroll
        for (int k = 0; k < MEMN; ++k) rv = fmaf(attn_s[el][k], Vs[el][k][m], rv);

        const float empty = (smk == 0.f) ? 1.f : 0.f;
        const float warm  = (t < 4) ? 1.f : 0.f;
        const float gate  = p * (1.f - empty) * (1.f - warm);
        const float e_val = gate * rv + (1.f - gate) * fv;

        es_out[r * 32 + m] = e_val;
        if (m == 0) ps_out[r] = p;

        const bool wr = (gate < 0.5f) || (warm > 0.f);
        __syncthreads();   // all reads of Ks/Vs/Tf/msk done before updates

        if (wr) { Ks[el][ei][m] = fk; Vs[el][ei][m] = fv; }

        // timer update: T = T*0.85 + bump*(1 - T*0.85); bumped slot == exactly 1.0f
        const float x = Tf * 0.85f;
        const bool bump = wr ? (m == ei) : (m == ai);
        Tf = bump ? (x + (1.f - x)) : x;
        if (wr && m == ei) msk = 1.f;
        __syncthreads();   // updates visible before next iteration
    }
}

// ---------------------------------------------------------------------------
extern "C" void kernel_launch(void* const* d_in, const int* in_sizes, int n_in,
                              void* d_out, int out_size, void* d_ws, size_t ws_size,
                              hipStream_t stream) {
    const float* h   = (const float*)d_in[0];
    const float* Wg  = (const float*)d_in[1];
    const float* bg  = (const float*)d_in[2];
    const float* Wq  = (const float*)d_in[3];
    const float* bq  = (const float*)d_in[4];
    const float* Wfk = (const float*)d_in[5];
    const float* bfk = (const float*)d_in[6];
    const float* Wfv = (const float*)d_in[7];
    const float* bfv = (const float*)d_in[8];

    // workspace layout: G[RTOT], Q[RTOT*32], FK[RTOT*32], FV[RTOT*32]
    float* G   = (float*)d_ws;
    float* Qp  = G + RTOT;
    float* FKp = Qp + (size_t)RTOT * 32;
    float* FVp = FKp + (size_t)RTOT * 32;

    proj_kernel<<<RTOT / BM, 256, 0, stream>>>(h, Wg, bg, Wq, bq, Wfk, bfk,
                                               Wfv, bfv, G, Qp, FKp, FVp);
    recur_kernel<<<BSZ / 4, 128, 0, stream>>>(G, Qp, FKp, FVp, (float*)d_out);
}

// Round 2
// 1102.647 us; speedup vs baseline: 1.0705x; 1.0705x over previous
//
#include <hip/hip_runtime.h>
#include <cmath>

// Problem constants
#define BSZ   2048
#define TSTEP 64
#define HDIM  1024
#define RTOT  (BSZ * TSTEP)   // 131072 rows
#define MEMN  32

// ---------------------------------------------------------------------------
// Kernel 1: projection GEMM  (RTOT x HDIM) @ (HDIM x 97) -> G, Q, FK, FV
// Columns: 0..31 = query, 32..63 = fk, 64..95 = fv, 96 = gate (sigmoid).
// fp32 vector GEMM. BM=256, BN=128 (pad >=97 with zeros), BK=32.
// 16x8 per-thread register tile -> LDS return BW (0.75 B/FMA) sits under the
// scalar-FMA floor; staging ds_writes remapped to 2-way (free) bank pattern.
// ---------------------------------------------------------------------------
constexpr int BM = 256, BN = 128, BK = 32;

__global__ __launch_bounds__(256, 2) void proj_kernel(
    const float* __restrict__ h,
    const float* __restrict__ Wg,  const float* __restrict__ bg,
    const float* __restrict__ Wq,  const float* __restrict__ bq,
    const float* __restrict__ Wfk, const float* __restrict__ bfk,
    const float* __restrict__ Wfv, const float* __restrict__ bfv,
    float* __restrict__ G, float* __restrict__ Qo,
    float* __restrict__ FKo, float* __restrict__ FVo)
{
    __shared__ __align__(16) float Xs[BK][BM + 4];  // Xs[k][row] (stride 260: b128-aligned)
    __shared__ __align__(16) float Ws[BK][BN + 4];  // Ws[k][col] (stride 132: b128-aligned)

    const int tid  = threadIdx.x;
    const int tx   = tid & 15;    // 0..15 col groups
    const int ty   = tid >> 4;    // 0..15 row groups
    const int row0 = blockIdx.x * BM;

    float acc[16][8] = {};

    for (int k0 = 0; k0 < HDIM; k0 += BK) {
        // --- stage X: thread tid copies row (row0+tid), cols [k0,k0+32) ---
        // ds_write bank = (quad*4 + tid) % 32 -> 2-way across 64 lanes (free).
        {
            const float* src = &h[(size_t)(row0 + tid) * HDIM + k0];
#pragma unroll
            for (int q = 0; q < 8; ++q) {
                const float4 v = *reinterpret_cast<const float4*>(src + q * 4);
                Xs[q * 4 + 0][tid] = v.x;
                Xs[q * 4 + 1][tid] = v.y;
                Xs[q * 4 + 2][tid] = v.z;
                Xs[q * 4 + 3][tid] = v.w;
            }
        }
        // --- stage W: task -> (nn = task&127, kq = task>>7); 2-way writes ---
#pragma unroll
        for (int it = 0; it < 4; ++it) {
            const int task = tid + it * 256;
            const int nn   = task & 127;
            const int kq   = task >> 7;      // 0..7
            float4 wv = make_float4(0.f, 0.f, 0.f, 0.f);
            const float* src = nullptr;
            if (nn < 32)       src = Wq  + (size_t)nn * HDIM;
            else if (nn < 64)  src = Wfk + (size_t)(nn - 32) * HDIM;
            else if (nn < 96)  src = Wfv + (size_t)(nn - 64) * HDIM;
            else if (nn == 96) src = Wg;
            if (src) wv = *reinterpret_cast<const float4*>(&src[k0 + kq * 4]);
            Ws[kq * 4 + 0][nn] = wv.x;
            Ws[kq * 4 + 1][nn] = wv.y;
            Ws[kq * 4 + 2][nn] = wv.z;
            Ws[kq * 4 + 3][nn] = wv.w;
        }
        __syncthreads();

        for (int k = 0; k < BK; ++k) {
            float av[16], bv[8];
#pragma unroll
            for (int g = 0; g < 4; ++g) {
                const float4 a = *reinterpret_cast<const float4*>(&Xs[k][g * 64 + ty * 4]);
                av[g * 4 + 0] = a.x; av[g * 4 + 1] = a.y;
                av[g * 4 + 2] = a.z; av[g * 4 + 3] = a.w;
            }
            const float4 b0 = *reinterpret_cast<const float4*>(&Ws[k][tx * 4]);
            const float4 b1 = *reinterpret_cast<const float4*>(&Ws[k][64 + tx * 4]);
            bv[0] = b0.x; bv[1] = b0.y; bv[2] = b0.z; bv[3] = b0.w;
            bv[4] = b1.x; bv[5] = b1.y; bv[6] = b1.z; bv[7] = b1.w;
#pragma unroll
            for (int i = 0; i < 16; ++i)
#pragma unroll
                for (int j = 0; j < 8; ++j)
                    acc[i][j] = fmaf(av[i], bv[j], acc[i][j]);
        }
        __syncthreads();
    }

    // --- epilogue: row i -> (i>>2)*64 + ty*4 + (i&3); col j as round 1 ---
#pragma unroll
    for (int i = 0; i < 16; ++i) {
        const int rl = (i >> 2) * 64 + ty * 4 + (i & 3);
        const size_t r = (size_t)row0 + rl;
#pragma unroll
        for (int j = 0; j < 8; ++j) {
            const int c = (j < 4) ? (tx * 4 + j) : (64 + tx * 4 + (j - 4));
            const float v = acc[i][j];
            if (c < 32)        Qo [r * 32 + c]        = v + bq[c];
            else if (c < 64)   FKo[r * 32 + (c - 32)] = v + bfk[c - 32];
            else if (c < 96)   FVo[r * 32 + (c - 64)] = v + bfv[c - 64];
            else if (c == 96) {
                const float x = v + bg[0];
                G[r] = 1.f / (1.f + expf(-x));   // p_reuse
            }
        }
    }
}

// ---------------------------------------------------------------------------
// LDS-only barrier: orders LDS traffic across the block WITHOUT the
// __syncthreads() vmcnt(0) drain, so in-flight global prefetch loads and
// es stores stay in flight across iterations. All cross-lane communication
// in recur_kernel goes through LDS (lgkm), so this is sufficient.
// ---------------------------------------------------------------------------
__device__ __forceinline__ void lds_barrier() {
    asm volatile("s_waitcnt lgkmcnt(0)\n\ts_barrier" ::: "memory");
}

// ---------------------------------------------------------------------------
// Kernel 2: recurrence. One 32-lane half-wave per batch element.
// Block = 128 threads = 4 batch elements. Grid = 2048/4 = 512.
// K,V in LDS (row padded to 33 -> conflict-free rows AND columns).
// Tf, mask in registers (lane m owns slot m). Next-iteration q/fk/fv/p are
// register-pipelined; 3 lgkm-only barriers per iteration.
// ---------------------------------------------------------------------------
__global__ __launch_bounds__(128) void recur_kernel(
    const float* __restrict__ G,  const float* __restrict__ Qp,
    const float* __restrict__ FKp, const float* __restrict__ FVp,
    float* __restrict__ out)
{
    __shared__ float Ks[4][MEMN][33];
    __shared__ float Vs[4][MEMN][33];
    __shared__ float qs[4][MEMN];
    __shared__ float attn_s[4][MEMN];

    const int tid = threadIdx.x;
    const int el  = tid >> 5;          // 0..3 local batch element
    const int m   = tid & 31;          // slot index
    const size_t b = (size_t)blockIdx.x * 4 + el;

#pragma unroll
    for (int k = 0; k < MEMN; ++k) { Ks[el][m][k] = 0.f; Vs[el][m][k] = 0.f; }
    float Tf  = 0.f;
    float msk = 0.f;
    __syncthreads();

    const float scale = 0.17677669529663687f;  // 1/sqrt(32)
    float* es_out = out;
    float* ps_out = out + (size_t)RTOT * 32;

    size_t r = b * TSTEP;
    float q  = Qp [r * 32 + m];
    float fk = FKp[r * 32 + m];
    float fv = FVp[r * 32 + m];
    float p  = G[r];

    for (int t = 0; t < TSTEP; ++t) {
        // prefetch next step (clamped at the tail; re-load is harmless)
        const size_t rn = r + ((t < TSTEP - 1) ? 1 : 0);
        const float qn  = Qp [rn * 32 + m];
        const float fkn = FKp[rn * 32 + m];
        const float fvn = FVp[rn * 32 + m];
        const float pn  = G[rn];

        qs[el][m] = q;
        lds_barrier();   // qs visible; prior iter's K/V updates visible

        // logits[m] = dot(K[m][:], q) * scale, masked
        float accv = 0.f;
#pragma unroll
        for (int k = 0; k < MEMN; ++k) accv = fmaf(Ks[el][m][k], qs[el][k], accv);
        const float lg = accv * scale + (1.f - msk) * (-1e9f);

        // softmax over 32 lanes
        float mx = lg;
#pragma unroll
        for (int d = 16; d >= 1; d >>= 1) mx = fmaxf(mx, __shfl_xor(mx, d));
        const float pe = expf(lg - mx);
        float ssum = pe;
#pragma unroll
        for (int d = 16; d >= 1; d >>= 1) ssum += __shfl_xor(ssum, d);
        const float attn = pe / ssum;
        attn_s[el][m] = attn;

        // mask sum (empty_row)
        float smk = msk;
#pragma unroll
        for (int d = 16; d >= 1; d >>= 1) smk += __shfl_xor(smk, d);

        // argmax(attn), first-index tie-break (jnp.argmax semantics)
        float av = attn; int ai = m;
#pragma unroll
        for (int d = 16; d >= 1; d >>= 1) {
            const float ov = __shfl_xor(av, d);
            const int   oi = __shfl_xor(ai, d);
            if (ov > av || (ov == av && oi < ai)) { av = ov; ai = oi; }
        }
        // argmin(Tf + mask*0.001), first-index tie-break (jnp.argmin)
        float evv = Tf + msk * 0.001f; int ei = m;
#pragma unroll
        for (int d = 16; d >= 1; d >>= 1) {
            const float ov = __shfl_xor(evv, d);
            const int   oi = __shfl_xor(ei, d);
            if (ov < evv || (ov == evv && oi < ei)) { evv = ov; ei = oi; }
        }
        lds_barrier();   // attn_s visible

        // retrv[m] = sum_k attn[k] * V[k][m]
        float rv = 0.f;
#pragma unroll
        for (int k = 0; k < MEMN; ++k) rv = fmaf(attn_s[el][k], Vs[el][k][m], rv);

        const float empty = (smk == 0.f) ? 1.f : 0.f;
        const float warm  = (t < 4) ? 1.f : 0.f;
        const float gate  = p * (1.f - empty) * (1.f - warm);
        const float e_val = gate * rv + (1.f - gate) * fv;

        es_out[r * 32 + m] = e_val;
        if (m == 0) ps_out[r] = p;

        const bool wr = (gate < 0.5f) || (warm > 0.f);
        lds_barrier();   // all reads of Ks/Vs/attn_s done before updates

        if (wr) { Ks[el][ei][m] = fk; Vs[el][ei][m] = fv; }

        const float x = Tf * 0.85f;
        const bool bump = wr ? (m == ei) : (m == ai);
        Tf = bump ? (x + (1.f - x)) : x;
        if (wr && m == ei) msk = 1.f;
        // next iteration's first lds_barrier orders these updates vs reads

        q = qn; fk = fkn; fv = fvn; p = pn; r = rn;
    }
}

// ---------------------------------------------------------------------------
extern "C" void kernel_launch(void* const* d_in, const int* in_sizes, int n_in,
                              void* d_out, int out_size, void* d_ws, size_t ws_size,
                              hipStream_t stream) {
    const float* h   = (const float*)d_in[0];
    const float* Wg  = (const float*)d_in[1];
    const float* bg  = (const float*)d_in[2];
    const float* Wq  = (const float*)d_in[3];
    const float* bq  = (const float*)d_in[4];
    const float* Wfk = (const float*)d_in[5];
    const float* bfk = (const float*)d_in[6];
    const float* Wfv = (const float*)d_in[7];
    const float* bfv = (const float*)d_in[8];

    // workspace: G[RTOT], Q[RTOT*32], FK[RTOT*32], FV[RTOT*32]
    float* G   = (float*)d_ws;
    float* Qp  = G + RTOT;
    float* FKp = Qp + (size_t)RTOT * 32;
    float* FVp = FKp + (size_t)RTOT * 32;

    proj_kernel<<<RTOT / BM, 256, 0, stream>>>(h, Wg, bg, Wq, bq, Wfk, bfk,
                                               Wfv, bfv, G, Qp, FKp, FVp);
    recur_kernel<<<BSZ / 4, 128, 0, stream>>>(G, Qp, FKp, FVp, (float*)d_out);
}